// Round 19
// baseline (305.443 us; speedup 1.0000x reference)
//
#include <hip/hip_runtime.h>
#include <hip/hip_bf16.h>

typedef unsigned short u16;
typedef short short8 __attribute__((ext_vector_type(8)));
typedef unsigned short ushort8 __attribute__((ext_vector_type(8)));
typedef float f32x4 __attribute__((ext_vector_type(4)));

// ---------------- helpers ----------------
static __device__ __forceinline__ u16 f2bf(float f) {
  unsigned u = __builtin_bit_cast(unsigned, f);
  unsigned r = (u + 0x7fffu + ((u >> 16) & 1u)) >> 16;  // RTNE
  return (u16)r;
}
static __device__ __forceinline__ float bf2f(u16 h) {
  unsigned u = ((unsigned)h) << 16;
  return __builtin_bit_cast(float, u);
}

// direct global->LDS DMA, 16B per lane; LDS dest is wave-uniform base + lane*16
static __device__ __forceinline__ void gload_lds16(const u16* g, u16* l) {
  __builtin_amdgcn_global_load_lds(
      (const __attribute__((address_space(1))) void*)g,
      (__attribute__((address_space(3))) void*)l, 16, 0, 0);
}

// =====================================================================
// Permuted X layout (chunk-uniform; W0 columns permuted identically so
// GEMM0 is invariant):
//   [0:256) fv | [256:281) copies | [288:524) trig | rest zeros
// scalar slots sc[22]: 0-2 pts, 3-5 vdir, 6-8 nrm, 9 density, 10-12 spos,
//                      13-15 var, 16-18 ray, 19-21 sdir
// =====================================================================

// ---------------- merged weight/table prep ----------------
static __device__ void prep_w0_body(const float* __restrict__ v,
                                    const float* __restrict__ g,
                                    u16* __restrict__ out, int row, int lane) {
  double s = 0.0;
  for (int k = lane; k < 517; k += 64) {
    double x = (double)v[(size_t)row * 517 + k];
    s += x * x;
  }
#pragma unroll
  for (int off = 32; off; off >>= 1) s += __shfl_xor(s, off);
  double scale = (double)g[row] / sqrt(s);

  for (int j = lane; j < 576; j += 64) {
    int orig = -1;
    if (j < 256) {
      orig = 9 + j;
    } else if (j < 281) {
      int e = j - 256;
      if (e < 9)       orig = e;
      else if (e < 12) orig = 265 + (e - 9);
      else if (e == 12) orig = 328;
      else if (e < 16) orig = 337 + (e - 13);
      else if (e < 19) orig = 400 + (e - 16);
      else if (e < 22) orig = 463 + (e - 19);
      else if (e < 25) orig = 490 + (e - 22);
    } else if (j >= 288 && j < 524) {
      int t = j - 288;
      if (t < 60)       orig = 268 + t;
      else if (t < 68)  orig = 329 + (t - 60);
      else if (t < 128) orig = 340 + (t - 68);
      else if (t < 188) orig = 403 + (t - 128);
      else if (t < 212) orig = 466 + (t - 188);
      else if (t < 236) orig = 493 + (t - 212);
    }
    float wv = (orig >= 0) ? (float)((double)v[(size_t)row * 517 + orig] * scale) : 0.0f;
    out[(size_t)row * 576 + j] = f2bf(wv);
  }
}

static __device__ void prep_w_body(const float* __restrict__ v,
                                   const float* __restrict__ g,
                                   u16* __restrict__ out, int row, int lane) {
  double s = 0.0;
  for (int k = lane; k < 512; k += 64) {
    double x = (double)v[(size_t)row * 512 + k];
    s += x * x;
  }
#pragma unroll
  for (int off = 32; off; off >>= 1) s += __shfl_xor(s, off);
  double scale = (double)g[row] / sqrt(s);
  for (int k = lane; k < 512; k += 64)
    out[(size_t)row * 512 + k] = f2bf((float)((double)v[(size_t)row * 512 + k] * scale));
}

static __device__ void prep_w4_body(const float* __restrict__ v,
                                    const float* __restrict__ g,
                                    float* __restrict__ out, int row, int lane) {
  double s = 0.0;
  for (int k = lane; k < 512; k += 64) {
    double x = (double)v[(size_t)row * 512 + k];
    s += x * x;
  }
#pragma unroll
  for (int off = 32; off; off >>= 1) s += __shfl_xor(s, off);
  double scale = (double)g[row] / sqrt(s);
  for (int k = lane; k < 512; k += 64)
    out[(size_t)row * 512 + k] = (float)((double)v[(size_t)row * 512 + k] * scale);
}

static __device__ void build_tb_body(u16* __restrict__ TB, int lane) {
  for (int i = lane; i < 320; i += 64) {
    const int j = 256 + i;
    unsigned d = 0;
    if (j < 281) {
      int e = j - 256;
      int src = -1;
      if (e < 9)       src = e;
      else if (e < 12) src = e - 9;
      else if (e == 12) src = 9;
      else if (e < 16) src = 10 + (e - 13);
      else if (e < 19) src = 13 + (e - 16);
      else if (e < 22) src = 16 + (e - 19);
      else if (e < 25) src = 19 + (e - 22);
      if (src >= 0) d = 1u | ((unsigned)src << 2);
    } else if (j >= 288 && j < 524) {
      int t = j - 288;
      if (t < 236) {
        int base, src0;
        if (t < 60)       { base = 0;   src0 = 0;  }
        else if (t < 68)  { base = 60;  src0 = 9;  }
        else if (t < 128) { base = 68;  src0 = 10; }
        else if (t < 188) { base = 128; src0 = 13; }
        else if (t < 212) { base = 188; src0 = 16; }
        else              { base = 212; src0 = 19; }
        int u = t - base;
        int f, cs, src;
        if (src0 == 9) { f = u >> 1; cs = u & 1; src = 9; }
        else { f = u / 6; int r = u - 6 * f; cs = (r >= 3) ? 1 : 0; src = src0 + (cs ? r - 3 : r); }
        d = 2u | ((unsigned)src << 2) | ((unsigned)cs << 7) | ((unsigned)f << 8);
      }
    }
    TB[i] = (u16)d;
  }
}

__global__ void prep_all(const float* __restrict__ v0, const float* __restrict__ g0,
                         const float* __restrict__ v1, const float* __restrict__ g1,
                         const float* __restrict__ v2, const float* __restrict__ g2,
                         const float* __restrict__ v3, const float* __restrict__ g3,
                         const float* __restrict__ v4, const float* __restrict__ g4,
                         u16* __restrict__ W0, u16* __restrict__ W1,
                         u16* __restrict__ W2, u16* __restrict__ W3,
                         float* __restrict__ W4, u16* __restrict__ TB) {
  const int b = blockIdx.x;
  const int lane = threadIdx.x;
  if (b < 512)       prep_w0_body(v0, g0, W0, b, lane);
  else if (b < 1024) prep_w_body(v1, g1, W1, b - 512, lane);
  else if (b < 1536) prep_w_body(v2, g2, W2, b - 1024, lane);
  else if (b < 2048) prep_w_body(v3, g3, W3, b - 1536, lane);
  else if (b == 2048) {
    for (int r = 0; r < 3; ++r) prep_w4_body(v4, g4, W4, r, lane);
  } else {
    build_tb_body(TB, lane);
  }
}

// ---------------- phase A: ball-query scan, one WAVE per point ----------------
__global__ __launch_bounds__(256) void scan_kernel(
    const float* __restrict__ pts, const float* __restrict__ phys,
    u16* __restrict__ idxbuf) {
  const int m = (int)((blockIdx.x * blockDim.x + threadIdx.x) >> 6);
  const int lane = (int)(threadIdx.x & 63);

  const double qx = (double)pts[m * 3 + 0];
  const double qy = (double)pts[m * 3 + 1];
  const double qz = (double)pts[m * 3 + 2];

  u16* __restrict__ row = idxbuf + (size_t)m * 24;

  int found = 0;
  for (int base = 0; base < 4096 && found < 20; base += 64) {
    const int j = base + lane;
    const double px = (double)phys[j * 3 + 0];
    const double py = (double)phys[j * 3 + 1];
    const double pz = (double)phys[j * 3 + 2];
    const double dx = px - qx, dy = py - qy, dz = pz - qz;
    const double d2 = dx * dx + dy * dy + dz * dz;   // fp64: selection must match np ref
    const bool valid = d2 < 81.0;
    const unsigned long long mb = __ballot(valid);
    const int rank = found + __popcll(mb & ((1ull << lane) - 1ull));
    if (valid && rank < 20) row[rank] = (u16)j;
    found += __popcll(mb);
    if (found > 20) found = 20;
  }
  if (lane == 0) row[20] = (u16)found;
}

// ---------------- phase B: gather + stats, one LANE per point ----------------
__global__ __launch_bounds__(256) void gstats_kernel(
    const float* __restrict__ pts, const float* __restrict__ phys,
    const float* __restrict__ cam, const u16* __restrict__ idxbuf,
    float* __restrict__ Pbuf) {
  const int i = blockIdx.x * 256 + threadIdx.x;

  const double qx = (double)pts[i * 3 + 0];
  const double qy = (double)pts[i * 3 + 1];
  const double qz = (double)pts[i * 3 + 2];

  const u16* __restrict__ row = idxbuf + (size_t)i * 24;
  const int cnt = (int)row[20];

  int nnn = 0;
  double w_sum = 0, wpx = 0, wpy = 0, wpz = 0;
  double Sx = 0, Sy = 0, Sz = 0, Qx = 0, Qy = 0, Qz = 0;

#pragma unroll
  for (int s = 0; s < 20; ++s) {
    if (s < cnt) {
      const int j = (int)row[s];
      const double px = (double)phys[j * 3 + 0];
      const double py = (double)phys[j * 3 + 1];
      const double pz = (double)phys[j * 3 + 2];
      const double dx = px - qx, dy = py - qy, dz = pz - qz;
      const double d2 = dx * dx + dy * dy + dz * dz;
      const float d2f = (float)d2;
      float wf = 1.0f - d2f * sqrtf(d2f) * (1.0f / 729.0f);
      if (wf < 0.0f) wf = 0.0f;
      const double w = (double)wf;
      w_sum += w; wpx += w * px; wpy += w * py; wpz += w * pz;
      if (d2 != 0.0) {
        nnn += 1;
        Sx += dx; Sy += dy; Sz += dz;
        Qx += dx * dx; Qy += dy * dy; Qz += dz * dz;
      }
    }
  }

  {
    const float q2f = (float)(qx * qx + qy * qy + qz * qz);
    float wpad = 1.0f - q2f * sqrtf(q2f) * (1.0f / 729.0f);
    if (wpad < 0.0f) wpad = 0.0f;
    w_sum += (double)(20 - cnt) * (double)wpad;
  }

  const double inv_denom = 1.0 / (w_sum + 1e-12);
  const double sposx = wpx * inv_denom, sposy = wpy * inv_denom, sposz = wpz * inv_denom;

  const double inv_nd = 1.0 / ((double)nnn + 1e-12);
  const double vmx = Sx * inv_nd, vmy = Sy * inv_nd, vmz = Sz * inv_nd;
  const float vax = (float)((Qx - 2.0 * vmx * Sx + (double)nnn * vmx * vmx) * inv_nd);
  const float vay = (float)((Qy - 2.0 * vmy * Sy + (double)nnn * vmy * vmy) * inv_nd);
  const float vaz = (float)((Qz - 2.0 * vmz * Sz + (double)nnn * vmz * vmz) * inv_nd);

  const double ddx = sposx - (double)cam[0];
  const double ddy = sposy - (double)cam[1];
  const double ddz = sposz - (double)cam[2];
  const double inv_dnm = 1.0 / sqrt(ddx * ddx + ddy * ddy + ddz * ddz);

  f32x4* out = (f32x4*)(Pbuf + (size_t)i * 12);
  f32x4 o0, o1, o2;
  o0[0] = (float)w_sum; o0[1] = (float)sposx; o0[2] = (float)sposy; o0[3] = (float)sposz;
  o1[0] = vax; o1[1] = vay; o1[2] = vaz; o1[3] = (float)(ddx * inv_dnm);
  o2[0] = (float)(ddy * inv_dnm); o2[1] = (float)(ddz * inv_dnm); o2[2] = 0.0f; o2[3] = 0.0f;
  out[0] = o0; out[1] = o1; out[2] = o2;
}

// ---------------- embed + write X: one THREAD per 8-col chunk ----------------
__global__ __launch_bounds__(576) void emb_kernel(
    const float* __restrict__ pts, const float* __restrict__ nrm,
    const float* __restrict__ vdir, const float* __restrict__ fv,
    const float* __restrict__ rdir, const float* __restrict__ Pbuf,
    const u16* __restrict__ TB, u16* __restrict__ X) {
  const int cc = (int)threadIdx.x;   // chunk 0..71
  const int y = (int)threadIdx.y;    // point in block 0..7
  const int m = blockIdx.x * 8 + y;

  __shared__ float sc[8][24];
  if (cc < 22) {
    float v;
    if (cc < 3)       v = pts[m * 3 + cc];
    else if (cc < 6)  v = vdir[m * 3 + (cc - 3)];
    else if (cc < 9)  v = nrm[m * 3 + (cc - 6)];
    else if (cc < 10) v = Pbuf[(size_t)m * 12 + 0];
    else if (cc < 13) v = Pbuf[(size_t)m * 12 + 1 + (cc - 10)];   // spos
    else if (cc < 16) v = Pbuf[(size_t)m * 12 + 4 + (cc - 13)];   // var
    else if (cc < 19) v = rdir[(m >> 7) * 3 + (cc - 16)];         // ray (reps=128)
    else              v = Pbuf[(size_t)m * 12 + 7 + (cc - 19)];   // sdir
    sc[y][cc] = v;
  }
  __syncthreads();

  u16* __restrict__ xp = X + (size_t)m * 576 + cc * 8;

  if (cc < 32) {
    const f32x4* fp = (const f32x4*)(fv + (size_t)m * 256 + cc * 8);
    f32x4 a = fp[0], b = fp[1];
    short8 o;
    o[0] = (short)f2bf(a[0]); o[1] = (short)f2bf(a[1]);
    o[2] = (short)f2bf(a[2]); o[3] = (short)f2bf(a[3]);
    o[4] = (short)f2bf(b[0]); o[5] = (short)f2bf(b[1]);
    o[6] = (short)f2bf(b[2]); o[7] = (short)f2bf(b[3]);
    *(short8*)xp = o;
  } else {
    ushort8 tb = *(const ushort8*)(TB + (size_t)(cc - 32) * 8);
    short8 o;
#pragma unroll
    for (int e = 0; e < 8; ++e) {
      const unsigned d = (unsigned)tb[e];
      const unsigned kind = d & 3u;
      float val = 0.0f;
      if (kind) {
        float x = sc[y][(d >> 2) & 31u];
        if (kind == 2u) {
          x *= __builtin_bit_cast(float, (127u + (d >> 8)) << 23);  // * 2^fexp (exact)
          float r = x * 0.15915494309189535f + (((d >> 7) & 1u) ? 0.25f : 0.0f);
          r -= floorf(r);
          val = __builtin_amdgcn_sinf(r);
        } else {
          val = x;
        }
      }
      o[e] = (short)f2bf(val);
    }
    *(short8*)xp = o;
  }
}

// ---------------- fused MLP: one block = 128 self-contained rows --------------
// Activations live in LDS act[128][576] bf16 (147 KB), 3-bit XOR chunk swizzle
// (slot = (ch&~7)|((ch^(row&7))&7)) applied identically at: layer-0 stage
// source, A-frag reads, epilogue writes, head reads -> conflict-free ds_reads.
// 8 waves (2 wm x 4 wn); wave tile 64 rows x 128 cols; acc[4][8] (128 VGPR).
// B (weights, L2-resident) streamed global->reg with explicit 2-deep named
// double-buffer (B0/B1) so the prefetch is issued one full K-step (~200+ cy)
// ahead -> covers L2 latency without barriers. K-loop has ZERO barriers
// (act is read-only during a layer); 2 barriers per layer around writeback.
// Head (512->3 + sigmoid) fused: block owns all 512 cols of its rows.
template <int KL>
static __device__ __forceinline__ void layer_pass(
    u16* act, const u16* __restrict__ W, const float* __restrict__ bias,
    int lane, int wm, int wn) {
  constexpr int NKS = KL / 32;
  const int fr = lane & 15;
  const int hi = lane >> 4;
  f32x4 acc[4][8] = {};

  const u16* __restrict__ Wb = W + (size_t)(wn * 128 + fr) * KL + hi * 8;

#define LOADB(dst, ks)                                                         \
  _Pragma("unroll")                                                            \
  for (int fn_ = 0; fn_ < 8; ++fn_)                                            \
    dst[fn_] = *(const short8*)(Wb + (size_t)fn_ * 16 * KL + (ks) * 32);

#define COMPUTE(Bregs, ks)                                                     \
  {                                                                            \
    short8 af_[4];                                                             \
    _Pragma("unroll")                                                          \
    for (int fm_ = 0; fm_ < 4; ++fm_) {                                        \
      const int row_ = wm * 64 + fm_ * 16 + fr;                                \
      const int ch_ = (ks) * 4 + hi;                                           \
      const int slot_ = (ch_ & ~7) | ((ch_ ^ (row_ & 7)) & 7);                 \
      af_[fm_] = *(const short8*)(act + (size_t)row_ * 576 + slot_ * 8);       \
    }                                                                          \
    _Pragma("unroll")                                                          \
    for (int fm_ = 0; fm_ < 4; ++fm_)                                          \
      _Pragma("unroll")                                                        \
      for (int fn_ = 0; fn_ < 8; ++fn_)                                        \
        acc[fm_][fn_] = __builtin_amdgcn_mfma_f32_16x16x32_bf16(               \
            af_[fm_], Bregs[fn_], acc[fm_][fn_], 0, 0, 0);                     \
  }

  short8 B0[8], B1[8];
  LOADB(B0, 0);
  for (int ks = 0; ks < NKS; ks += 2) {
    LOADB(B1, ks + 1);
    COMPUTE(B0, ks);
    if (ks + 2 < NKS) LOADB(B0, ks + 2);
    COMPUTE(B1, ks + 1);
  }
#undef LOADB
#undef COMPUTE

  __syncthreads();  // all waves done reading act before overwrite

  const int lr = lane >> 4, lc = lane & 15;
#pragma unroll
  for (int fn = 0; fn < 8; ++fn) {
    const int col = wn * 128 + fn * 16 + lc;
    const float bv = bias[col];
    const int ch = col >> 3;
    const int ce = col & 7;
#pragma unroll
    for (int fm = 0; fm < 4; ++fm) {
      const int rowb = wm * 64 + fm * 16 + lr * 4;
#pragma unroll
      for (int rg = 0; rg < 4; ++rg) {
        const int row = rowb + rg;
        const int slot = (ch & ~7) | ((ch ^ (row & 7)) & 7);
        float vv = fmaxf(acc[fm][fn][rg] + bv, 0.0f);
        act[(size_t)row * 576 + slot * 8 + ce] = f2bf(vv);
      }
    }
  }

  __syncthreads();  // writeback visible before next layer reads
}

__global__ __launch_bounds__(512) void fused_mlp(
    const u16* __restrict__ X,
    const u16* __restrict__ W0, const float* __restrict__ b0,
    const u16* __restrict__ W1, const float* __restrict__ b1,
    const u16* __restrict__ W2, const float* __restrict__ b2,
    const u16* __restrict__ W3, const float* __restrict__ b3,
    const float* __restrict__ W4, const float* __restrict__ b4,
    float* __restrict__ out) {
  __shared__ __align__(16) u16 act[128 * 576];  // 147456 B

  const int t = (int)threadIdx.x;
  const int lane = t & 63;
  const int wid = t >> 6;
  const int wm = wid >> 2;   // 0..1 (row half of 128)
  const int wn = wid & 3;    // 0..3 (col quarter of 512)
  const int m0 = blockIdx.x * 128;

  // ---- stage X[m0..m0+127][0..575] -> act, pre-swizzled source, linear dest --
  {
    const int base_g = t & ~63;  // wave-uniform chunk base
#pragma unroll
    for (int i = 0; i < 18; ++i) {
      const int gb = i * 512 + base_g;
      const int d = gb + lane;
      const int row = d / 72;
      const int sc = d - row * 72;
      const int src = (sc & ~7) | ((sc ^ (row & 7)) & 7);
      gload_lds16(X + (size_t)(m0 + row) * 576 + src * 8, act + (size_t)gb * 8);
    }
  }
  __syncthreads();  // drains vmcnt -> act ready

  layer_pass<576>(act, W0, b0, lane, wm, wn);
  layer_pass<512>(act, W1, b1, lane, wm, wn);
  layer_pass<512>(act, W2, b2, lane, wm, wn);
  layer_pass<512>(act, W3, b3, lane, wm, wn);

  // ---- head: out[row] = sigmoid(H4[row] . W4^T + b4), 4 threads per row ----
  {
    const int row = t >> 2;
    const int part = t & 3;
    float s0 = 0.0f, s1 = 0.0f, s2 = 0.0f;
#pragma unroll
    for (int j = 0; j < 16; ++j) {
      const int ch = part * 16 + j;
      const int slot = (ch & ~7) | ((ch ^ (row & 7)) & 7);
      short8 v = *(const short8*)(act + (size_t)row * 576 + slot * 8);
#pragma unroll
      for (int e = 0; e < 8; ++e) {
        const float h = bf2f((u16)v[e]);
        const int col = ch * 8 + e;
        s0 += h * W4[col];
        s1 += h * W4[512 + col];
        s2 += h * W4[1024 + col];
      }
    }
    s0 += __shfl_xor(s0, 1); s1 += __shfl_xor(s1, 1); s2 += __shfl_xor(s2, 1);
    s0 += __shfl_xor(s0, 2); s1 += __shfl_xor(s1, 2); s2 += __shfl_xor(s2, 2);
    if (part == 0) {
      float* o = out + (size_t)(m0 + row) * 3;
      o[0] = 1.0f / (1.0f + expf(-(s0 + b4[0])));
      o[1] = 1.0f / (1.0f + expf(-(s1 + b4[1])));
      o[2] = 1.0f / (1.0f + expf(-(s2 + b4[2])));
    }
  }
}

// ---------------- launch ----------------
extern "C" void kernel_launch(void* const* d_in, const int* in_sizes, int n_in,
                              void* d_out, int out_size, void* d_ws, size_t ws_size,
                              hipStream_t stream) {
  const float* pts  = (const float*)d_in[0];
  const float* nrm  = (const float*)d_in[1];
  const float* vdir = (const float*)d_in[2];
  const float* fv   = (const float*)d_in[3];
  const float* phys = (const float*)d_in[4];
  const float* rdir = (const float*)d_in[5];
  const float* cam  = (const float*)d_in[6];
  const float* v0 = (const float*)d_in[7];  const float* g0 = (const float*)d_in[8];  const float* b0 = (const float*)d_in[9];
  const float* v1 = (const float*)d_in[10]; const float* g1 = (const float*)d_in[11]; const float* b1 = (const float*)d_in[12];
  const float* v2 = (const float*)d_in[13]; const float* g2 = (const float*)d_in[14]; const float* b2 = (const float*)d_in[15];
  const float* v3 = (const float*)d_in[16]; const float* g3 = (const float*)d_in[17]; const float* b3 = (const float*)d_in[18];
  const float* v4 = (const float*)d_in[19]; const float* g4 = (const float*)d_in[20]; const float* b4 = (const float*)d_in[21];

  char* ws = (char*)d_ws;
  u16*      W0 = (u16*)(ws + 0);            // 512*576*2 = 589824 (permuted cols)
  u16*      W1 = (u16*)(ws + 589824);       // 512*512*2 = 524288
  u16*      W2 = (u16*)(ws + 1114112);
  u16*      W3 = (u16*)(ws + 1638400);
  float*    W4 = (float*)(ws + 2162688);    // 3*512*4 = 6144
  u16*      TB = (u16*)(ws + 2168832);      // 320*2 = 640 (pad to 2304)
  u16*      Ix = (u16*)(ws + 2171136);      // 32768*24*2 = 1572864
  float*    Pb = (float*)(ws + 3744000);    // 32768*12*4 = 1572864
  u16*      X  = (u16*)(ws + 5316864);      // 32768*576*2 = 37748736 (permuted cols)

  prep_all<<<2050, 64, 0, stream>>>(v0, g0, v1, g1, v2, g2, v3, g3, v4, g4,
                                    W0, W1, W2, W3, W4, TB);

  scan_kernel<<<8192, 256, 0, stream>>>(pts, phys, Ix);
  gstats_kernel<<<128, 256, 0, stream>>>(pts, phys, cam, Ix, Pb);
  emb_kernel<<<4096, dim3(72, 8), 0, stream>>>(pts, nrm, vdir, fv, rdir, Pb, TB, X);

  fused_mlp<<<256, 512, 0, stream>>>(X, W0, b0, W1, b1, W2, b2, W3, b3, W4, b4,
                                     (float*)d_out);
}

// Round 20
// 151.899 us; speedup vs baseline: 2.0108x; 2.0108x over previous
//
#include <hip/hip_runtime.h>
#include <hip/hip_bf16.h>

typedef unsigned short u16;
typedef short short8 __attribute__((ext_vector_type(8)));
typedef unsigned short ushort8 __attribute__((ext_vector_type(8)));
typedef float f32x4 __attribute__((ext_vector_type(4)));

// ---------------- helpers ----------------
static __device__ __forceinline__ u16 f2bf(float f) {
  unsigned u = __builtin_bit_cast(unsigned, f);
  unsigned r = (u + 0x7fffu + ((u >> 16) & 1u)) >> 16;  // RTNE
  return (u16)r;
}
static __device__ __forceinline__ float bf2f(u16 h) {
  unsigned u = ((unsigned)h) << 16;
  return __builtin_bit_cast(float, u);
}

// direct global->LDS DMA, 16B per lane; LDS dest is wave-uniform base + lane*16
static __device__ __forceinline__ void gload_lds16(const u16* g, u16* l) {
  __builtin_amdgcn_global_load_lds(
      (const __attribute__((address_space(1))) void*)g,
      (__attribute__((address_space(3))) void*)l, 16, 0, 0);
}

// =====================================================================
// Permuted X layout (chunk-uniform; W0 columns permuted identically so
// GEMM0 is invariant):
//   [0:256) fv | [256:281) copies | [288:524) trig | rest zeros
// scalar slots sc[22]: 0-2 pts, 3-5 vdir, 6-8 nrm, 9 density, 10-12 spos,
//                      13-15 var, 16-18 ray, 19-21 sdir
// =====================================================================

// ---------------- merged weight/table prep ----------------
static __device__ void prep_w0_body(const float* __restrict__ v,
                                    const float* __restrict__ g,
                                    u16* __restrict__ out, int row, int lane) {
  double s = 0.0;
  for (int k = lane; k < 517; k += 64) {
    double x = (double)v[(size_t)row * 517 + k];
    s += x * x;
  }
#pragma unroll
  for (int off = 32; off; off >>= 1) s += __shfl_xor(s, off);
  double scale = (double)g[row] / sqrt(s);

  for (int j = lane; j < 576; j += 64) {
    int orig = -1;
    if (j < 256) {
      orig = 9 + j;
    } else if (j < 281) {
      int e = j - 256;
      if (e < 9)       orig = e;
      else if (e < 12) orig = 265 + (e - 9);
      else if (e == 12) orig = 328;
      else if (e < 16) orig = 337 + (e - 13);
      else if (e < 19) orig = 400 + (e - 16);
      else if (e < 22) orig = 463 + (e - 19);
      else if (e < 25) orig = 490 + (e - 22);
    } else if (j >= 288 && j < 524) {
      int t = j - 288;
      if (t < 60)       orig = 268 + t;
      else if (t < 68)  orig = 329 + (t - 60);
      else if (t < 128) orig = 340 + (t - 68);
      else if (t < 188) orig = 403 + (t - 128);
      else if (t < 212) orig = 466 + (t - 188);
      else if (t < 236) orig = 493 + (t - 212);
    }
    float wv = (orig >= 0) ? (float)((double)v[(size_t)row * 517 + orig] * scale) : 0.0f;
    out[(size_t)row * 576 + j] = f2bf(wv);
  }
}

static __device__ void prep_w_body(const float* __restrict__ v,
                                   const float* __restrict__ g,
                                   u16* __restrict__ out, int row, int lane) {
  double s = 0.0;
  for (int k = lane; k < 512; k += 64) {
    double x = (double)v[(size_t)row * 512 + k];
    s += x * x;
  }
#pragma unroll
  for (int off = 32; off; off >>= 1) s += __shfl_xor(s, off);
  double scale = (double)g[row] / sqrt(s);
  for (int k = lane; k < 512; k += 64)
    out[(size_t)row * 512 + k] = f2bf((float)((double)v[(size_t)row * 512 + k] * scale));
}

static __device__ void prep_w4_body(const float* __restrict__ v,
                                    const float* __restrict__ g,
                                    float* __restrict__ out, int row, int lane) {
  double s = 0.0;
  for (int k = lane; k < 512; k += 64) {
    double x = (double)v[(size_t)row * 512 + k];
    s += x * x;
  }
#pragma unroll
  for (int off = 32; off; off >>= 1) s += __shfl_xor(s, off);
  double scale = (double)g[row] / sqrt(s);
  for (int k = lane; k < 512; k += 64)
    out[(size_t)row * 512 + k] = (float)((double)v[(size_t)row * 512 + k] * scale);
}

static __device__ void build_tb_body(u16* __restrict__ TB, int lane) {
  for (int i = lane; i < 320; i += 64) {
    const int j = 256 + i;
    unsigned d = 0;
    if (j < 281) {
      int e = j - 256;
      int src = -1;
      if (e < 9)       src = e;
      else if (e < 12) src = e - 9;
      else if (e == 12) src = 9;
      else if (e < 16) src = 10 + (e - 13);
      else if (e < 19) src = 13 + (e - 16);
      else if (e < 22) src = 16 + (e - 19);
      else if (e < 25) src = 19 + (e - 22);
      if (src >= 0) d = 1u | ((unsigned)src << 2);
    } else if (j >= 288 && j < 524) {
      int t = j - 288;
      if (t < 236) {
        int base, src0;
        if (t < 60)       { base = 0;   src0 = 0;  }
        else if (t < 68)  { base = 60;  src0 = 9;  }
        else if (t < 128) { base = 68;  src0 = 10; }
        else if (t < 188) { base = 128; src0 = 13; }
        else if (t < 212) { base = 188; src0 = 16; }
        else              { base = 212; src0 = 19; }
        int u = t - base;
        int f, cs, src;
        if (src0 == 9) { f = u >> 1; cs = u & 1; src = 9; }
        else { f = u / 6; int r = u - 6 * f; cs = (r >= 3) ? 1 : 0; src = src0 + (cs ? r - 3 : r); }
        d = 2u | ((unsigned)src << 2) | ((unsigned)cs << 7) | ((unsigned)f << 8);
      }
    }
    TB[i] = (u16)d;
  }
}

__global__ void prep_all(const float* __restrict__ v0, const float* __restrict__ g0,
                         const float* __restrict__ v1, const float* __restrict__ g1,
                         const float* __restrict__ v2, const float* __restrict__ g2,
                         const float* __restrict__ v3, const float* __restrict__ g3,
                         const float* __restrict__ v4, const float* __restrict__ g4,
                         u16* __restrict__ W0, u16* __restrict__ W1,
                         u16* __restrict__ W2, u16* __restrict__ W3,
                         float* __restrict__ W4, u16* __restrict__ TB) {
  const int b = blockIdx.x;
  const int lane = threadIdx.x;
  if (b < 512)       prep_w0_body(v0, g0, W0, b, lane);
  else if (b < 1024) prep_w_body(v1, g1, W1, b - 512, lane);
  else if (b < 1536) prep_w_body(v2, g2, W2, b - 1024, lane);
  else if (b < 2048) prep_w_body(v3, g3, W3, b - 1536, lane);
  else if (b == 2048) {
    for (int r = 0; r < 3; ++r) prep_w4_body(v4, g4, W4, r, lane);
  } else {
    build_tb_body(TB, lane);
  }
}

// ---------------- phase A: ball-query scan, one WAVE per point ----------------
// idxbuf row (24 u16 per point): [0:20) neighbor indices (first-20 by index), [20] count
__global__ __launch_bounds__(256) void scan_kernel(
    const float* __restrict__ pts, const float* __restrict__ phys,
    u16* __restrict__ idxbuf) {
  const int m = (int)((blockIdx.x * blockDim.x + threadIdx.x) >> 6);
  const int lane = (int)(threadIdx.x & 63);

  const double qx = (double)pts[m * 3 + 0];
  const double qy = (double)pts[m * 3 + 1];
  const double qz = (double)pts[m * 3 + 2];

  u16* __restrict__ row = idxbuf + (size_t)m * 24;

  int found = 0;
  for (int base = 0; base < 4096 && found < 20; base += 64) {
    const int j = base + lane;
    const double px = (double)phys[j * 3 + 0];
    const double py = (double)phys[j * 3 + 1];
    const double pz = (double)phys[j * 3 + 2];
    const double dx = px - qx, dy = py - qy, dz = pz - qz;
    const double d2 = dx * dx + dy * dy + dz * dz;   // fp64: selection must match np ref
    const bool valid = d2 < 81.0;
    const unsigned long long mb = __ballot(valid);
    const int rank = found + __popcll(mb & ((1ull << lane) - 1ull));
    if (valid && rank < 20) row[rank] = (u16)j;
    found += __popcll(mb);
    if (found > 20) found = 20;
  }
  if (lane == 0) row[20] = (u16)found;
}

// ---------------- phase B: gather + stats, one LANE per point ----------------
// Pbuf per point (12 f32): density, spx,spy,spz, vax,vay,vaz, sdx,sdy,sdz, 0,0
__global__ __launch_bounds__(256) void gstats_kernel(
    const float* __restrict__ pts, const float* __restrict__ phys,
    const float* __restrict__ cam, const u16* __restrict__ idxbuf,
    float* __restrict__ Pbuf) {
  const int i = blockIdx.x * 256 + threadIdx.x;

  const double qx = (double)pts[i * 3 + 0];
  const double qy = (double)pts[i * 3 + 1];
  const double qz = (double)pts[i * 3 + 2];

  const u16* __restrict__ row = idxbuf + (size_t)i * 24;
  const int cnt = (int)row[20];

  int nnn = 0;
  double w_sum = 0, wpx = 0, wpy = 0, wpz = 0;
  double Sx = 0, Sy = 0, Sz = 0, Qx = 0, Qy = 0, Qz = 0;

#pragma unroll
  for (int s = 0; s < 20; ++s) {
    if (s < cnt) {
      const int j = (int)row[s];
      const double px = (double)phys[j * 3 + 0];
      const double py = (double)phys[j * 3 + 1];
      const double pz = (double)phys[j * 3 + 2];
      const double dx = px - qx, dy = py - qy, dz = pz - qz;
      const double d2 = dx * dx + dy * dy + dz * dz;
      const float d2f = (float)d2;
      float wf = 1.0f - d2f * sqrtf(d2f) * (1.0f / 729.0f);
      if (wf < 0.0f) wf = 0.0f;
      const double w = (double)wf;
      w_sum += w; wpx += w * px; wpy += w * py; wpz += w * pz;
      if (d2 != 0.0) {
        nnn += 1;
        Sx += dx; Sy += dy; Sz += dz;
        Qx += dx * dx; Qy += dy * dy; Qz += dz * dz;
      }
    }
  }

  {
    const float q2f = (float)(qx * qx + qy * qy + qz * qz);
    float wpad = 1.0f - q2f * sqrtf(q2f) * (1.0f / 729.0f);
    if (wpad < 0.0f) wpad = 0.0f;
    w_sum += (double)(20 - cnt) * (double)wpad;
  }

  const double inv_denom = 1.0 / (w_sum + 1e-12);
  const double sposx = wpx * inv_denom, sposy = wpy * inv_denom, sposz = wpz * inv_denom;

  const double inv_nd = 1.0 / ((double)nnn + 1e-12);
  const double vmx = Sx * inv_nd, vmy = Sy * inv_nd, vmz = Sz * inv_nd;
  const float vax = (float)((Qx - 2.0 * vmx * Sx + (double)nnn * vmx * vmx) * inv_nd);
  const float vay = (float)((Qy - 2.0 * vmy * Sy + (double)nnn * vmy * vmy) * inv_nd);
  const float vaz = (float)((Qz - 2.0 * vmz * Sz + (double)nnn * vmz * vmz) * inv_nd);

  const double ddx = sposx - (double)cam[0];
  const double ddy = sposy - (double)cam[1];
  const double ddz = sposz - (double)cam[2];
  const double inv_dnm = 1.0 / sqrt(ddx * ddx + ddy * ddy + ddz * ddz);

  f32x4* out = (f32x4*)(Pbuf + (size_t)i * 12);
  f32x4 o0, o1, o2;
  o0[0] = (float)w_sum; o0[1] = (float)sposx; o0[2] = (float)sposy; o0[3] = (float)sposz;
  o1[0] = vax; o1[1] = vay; o1[2] = vaz; o1[3] = (float)(ddx * inv_dnm);
  o2[0] = (float)(ddy * inv_dnm); o2[1] = (float)(ddz * inv_dnm); o2[2] = 0.0f; o2[3] = 0.0f;
  out[0] = o0; out[1] = o1; out[2] = o2;
}

// ---------------- embed + write X: one THREAD per 8-col chunk ----------------
__global__ __launch_bounds__(576) void emb_kernel(
    const float* __restrict__ pts, const float* __restrict__ nrm,
    const float* __restrict__ vdir, const float* __restrict__ fv,
    const float* __restrict__ rdir, const float* __restrict__ Pbuf,
    const u16* __restrict__ TB, u16* __restrict__ X) {
  const int cc = (int)threadIdx.x;   // chunk 0..71
  const int y = (int)threadIdx.y;    // point in block 0..7
  const int m = blockIdx.x * 8 + y;

  __shared__ float sc[8][24];
  if (cc < 22) {
    float v;
    if (cc < 3)       v = pts[m * 3 + cc];
    else if (cc < 6)  v = vdir[m * 3 + (cc - 3)];
    else if (cc < 9)  v = nrm[m * 3 + (cc - 6)];
    else if (cc < 10) v = Pbuf[(size_t)m * 12 + 0];
    else if (cc < 13) v = Pbuf[(size_t)m * 12 + 1 + (cc - 10)];   // spos
    else if (cc < 16) v = Pbuf[(size_t)m * 12 + 4 + (cc - 13)];   // var
    else if (cc < 19) v = rdir[(m >> 7) * 3 + (cc - 16)];         // ray (reps=128)
    else              v = Pbuf[(size_t)m * 12 + 7 + (cc - 19)];   // sdir
    sc[y][cc] = v;
  }
  __syncthreads();

  u16* __restrict__ xp = X + (size_t)m * 576 + cc * 8;

  if (cc < 32) {
    const f32x4* fp = (const f32x4*)(fv + (size_t)m * 256 + cc * 8);
    f32x4 a = fp[0], b = fp[1];
    short8 o;
    o[0] = (short)f2bf(a[0]); o[1] = (short)f2bf(a[1]);
    o[2] = (short)f2bf(a[2]); o[3] = (short)f2bf(a[3]);
    o[4] = (short)f2bf(b[0]); o[5] = (short)f2bf(b[1]);
    o[6] = (short)f2bf(b[2]); o[7] = (short)f2bf(b[3]);
    *(short8*)xp = o;
  } else {
    ushort8 tb = *(const ushort8*)(TB + (size_t)(cc - 32) * 8);
    short8 o;
#pragma unroll
    for (int e = 0; e < 8; ++e) {
      const unsigned d = (unsigned)tb[e];
      const unsigned kind = d & 3u;
      float val = 0.0f;
      if (kind) {
        float x = sc[y][(d >> 2) & 31u];
        if (kind == 2u) {
          x *= __builtin_bit_cast(float, (127u + (d >> 8)) << 23);  // * 2^fexp (exact)
          float r = x * 0.15915494309189535f + (((d >> 7) & 1u) ? 0.25f : 0.0f);
          r -= floorf(r);
          val = __builtin_amdgcn_sinf(r);
        } else {
          val = x;
        }
      }
      o[e] = (short)f2bf(val);
    }
    *(short8*)xp = o;
  }
}

// ---------------- bf16 MFMA GEMM: 256x256 tile, 8 waves, dbuf + counted vmcnt --
// R13 K-loop (proven): 512 threads = 8 waves (2 wm x 4 wn); wave owns 128x64
// output (acc[8][4]). LDS: 2 x (As 256x64 | Bs 256x64) bf16 = 128 KB staging;
// epilogue reuses as [256][264] bf16 bounce. Counted vmcnt(8); both-sides XOR
// swizzle; XCD-aware bijective block swizzle. Grid = 256 blocks = 1/CU.
// HEAD=true: 512->3 head partials from the LDS bounce instead of storing C.
template <int KTILES, bool HEAD>
__global__ __launch_bounds__(512, 2) void gemm_relu(const u16* __restrict__ A,
                                                    const u16* __restrict__ B,
                                                    const float* __restrict__ bias,
                                                    u16* __restrict__ C,
                                                    const float* __restrict__ W4h,
                                                    float* __restrict__ Pp) {
  constexpr int K = KTILES * 64;
  constexpr int EPS = 264;                   // epilogue row stride (256 + 8 pad)
  __shared__ __align__(16) u16 smem[67584];  // 132 KB (staging needs 65536 u16)
#define AS_(b, r) (smem + (size_t)(b) * 32768 + (size_t)(r) * 64)
#define BS_(b, r) (smem + (size_t)(b) * 32768 + 16384 + (size_t)(r) * 64)

  const int t = threadIdx.x;
  const int lane = t & 63;
  const int wid = t >> 6;
  const int wm = wid >> 2;   // 0..1: row half (128 rows)
  const int wn = wid & 3;    // 0..3: col quarter (64 cols)

  // XCD-aware bijective swizzle: 256 blocks, 8 XCDs -> 32 contiguous wgids each.
  const int bid = blockIdx.x;
  const int wgid = (bid & 7) * 32 + (bid >> 3);
  const int n0 = (wgid & 1) * 256;
  const int m0 = (wgid >> 1) * 256;

  const int srow = lane >> 3;                      // 0..7 within an 8-row slab
  const int gcol = ((lane & 7) ^ srow) * 8;        // swizzled source chunk

  f32x4 acc[8][4] = {};

#define STAGE(kt, b)                                                           \
  {                                                                            \
    const int k0_ = (kt) * 64;                                                 \
    _Pragma("unroll")                                                          \
    for (int i_ = 0; i_ < 4; ++i_) {                                           \
      const int rbase_ = wid * 8 + i_ * 64;                                    \
      const int row_ = rbase_ + srow;                                          \
      gload_lds16(A + (size_t)(m0 + row_) * K + k0_ + gcol, AS_(b, rbase_));   \
      gload_lds16(B + (size_t)(n0 + row_) * K + k0_ + gcol, BS_(b, rbase_));   \
    }                                                                          \
  }

  STAGE(0, 0);

  const int rsw = lane & 7;
  for (int kt = 0; kt < KTILES; ++kt) {
    const int cur = kt & 1;
    __builtin_amdgcn_s_barrier();   // all waves done reading buf[cur^1]'s old tile
    if (kt + 1 < KTILES) {
      STAGE(kt + 1, cur ^ 1);
      asm volatile("s_waitcnt vmcnt(8)" ::: "memory");   // tile kt's 8 DMAs done
    } else {
      asm volatile("s_waitcnt vmcnt(0)" ::: "memory");
    }
    __builtin_amdgcn_s_barrier();   // every wave's tile-kt DMAs complete
#pragma unroll
    for (int ks = 0; ks < 2; ++ks) {
      short8 af[8], bfv[4];
      const int fr = lane & 15;
      const int cc = ((ks * 4 + (lane >> 4)) ^ rsw) * 8;
#pragma unroll
      for (int f = 0; f < 8; ++f)
        af[f] = *(const short8*)(AS_(cur, wm * 128 + f * 16 + fr) + cc);
#pragma unroll
      for (int f = 0; f < 4; ++f)
        bfv[f] = *(const short8*)(BS_(cur, wn * 64 + f * 16 + fr) + cc);
#pragma unroll
      for (int fm = 0; fm < 8; ++fm)
#pragma unroll
        for (int fn = 0; fn < 4; ++fn)
          acc[fm][fn] = __builtin_amdgcn_mfma_f32_16x16x32_bf16(af[fm], bfv[fn], acc[fm][fn], 0, 0, 0);
    }
  }
#undef STAGE

  // ---- epilogue: bias+relu -> LDS [256][264] bf16 bounce ----
  __syncthreads();  // all waves done reading staging LDS before epi overwrite
  const int lr = lane >> 4, lc = lane & 15;
#pragma unroll
  for (int fn = 0; fn < 4; ++fn) {
    const int tcol = wn * 64 + fn * 16 + lc;
    const float bv = bias[n0 + tcol];
#pragma unroll
    for (int fm = 0; fm < 8; ++fm) {
      const int rowb = wm * 128 + fm * 16 + lr * 4;
#pragma unroll
      for (int rg = 0; rg < 4; ++rg) {
        float vv = fmaxf(acc[fm][fn][rg] + bv, 0.0f);
        smem[(size_t)(rowb + rg) * EPS + tcol] = f2bf(vv);
      }
    }
  }
  __syncthreads();

  if (!HEAD) {
    // wave stores rows [wid*32, wid*32+32): 2 rows x 512B contiguous per instr
#pragma unroll
    for (int it = 0; it < 16; ++it) {
      const int row = wid * 32 + it * 2 + (lane >> 5);
      const int ch = lane & 31;
      short8 v = *(const short8*)(smem + (size_t)row * EPS + ch * 8);
      *(short8*)(C + (size_t)(m0 + row) * 512 + n0 + ch * 8) = v;
    }
  } else {
    // head: thread pair (row = t>>1, half = t&1) dots 128 cols with W4h.
    const int row = t >> 1;
    const int half = t & 1;
    float s0 = 0.0f, s1 = 0.0f, s2 = 0.0f;
    const int cbase = half * 128;
#pragma unroll
    for (int ch = 0; ch < 16; ++ch) {
      short8 v = *(const short8*)(smem + (size_t)row * EPS + cbase + ch * 8);
#pragma unroll
      for (int e = 0; e < 8; ++e) {
        const float h = bf2f((u16)v[e]);
        const int col = n0 + cbase + ch * 8 + e;
        s0 += h * W4h[0 * 512 + col];
        s1 += h * W4h[1 * 512 + col];
        s2 += h * W4h[2 * 512 + col];
      }
    }
    s0 += __shfl_xor(s0, 1);
    s1 += __shfl_xor(s1, 1);
    s2 += __shfl_xor(s2, 1);
    if (half == 0) {
      float* p = Pp + ((size_t)(n0 >> 8) * 32768 + (m0 + row)) * 4;
      p[0] = s0; p[1] = s1; p[2] = s2;
    }
  }
#undef AS_
#undef BS_
}

// ---------------- sigmoid over head partials: out = sigma(P0+P1+b4) ----------
__global__ __launch_bounds__(256) void sigmoid_kernel(const float* __restrict__ Pp,
                                                      const float* __restrict__ b4,
                                                      float* __restrict__ out) {
  const int m = blockIdx.x * 256 + threadIdx.x;   // 32768 points
  const f32x4 p0 = *(const f32x4*)(Pp + (size_t)m * 4);
  const f32x4 p1 = *(const f32x4*)(Pp + (size_t)(32768 + m) * 4);
#pragma unroll
  for (int r = 0; r < 3; ++r) {
    const float v = p0[r] + p1[r] + b4[r];
    out[(size_t)m * 3 + r] = 1.0f / (1.0f + expf(-v));
  }
}

// ---------------- launch ----------------
extern "C" void kernel_launch(void* const* d_in, const int* in_sizes, int n_in,
                              void* d_out, int out_size, void* d_ws, size_t ws_size,
                              hipStream_t stream) {
  const float* pts  = (const float*)d_in[0];
  const float* nrm  = (const float*)d_in[1];
  const float* vdir = (const float*)d_in[2];
  const float* fv   = (const float*)d_in[3];
  const float* phys = (const float*)d_in[4];
  const float* rdir = (const float*)d_in[5];
  const float* cam  = (const float*)d_in[6];
  const float* v0 = (const float*)d_in[7];  const float* g0 = (const float*)d_in[8];  const float* b0 = (const float*)d_in[9];
  const float* v1 = (const float*)d_in[10]; const float* g1 = (const float*)d_in[11]; const float* b1 = (const float*)d_in[12];
  const float* v2 = (const float*)d_in[13]; const float* g2 = (const float*)d_in[14]; const float* b2 = (const float*)d_in[15];
  const float* v3 = (const float*)d_in[16]; const float* g3 = (const float*)d_in[17]; const float* b3 = (const float*)d_in[18];
  const float* v4 = (const float*)d_in[19]; const float* g4 = (const float*)d_in[20]; const float* b4 = (const float*)d_in[21];

  char* ws = (char*)d_ws;
  u16*      W0 = (u16*)(ws + 0);            // 512*576*2 = 589824 (permuted cols)
  u16*      W1 = (u16*)(ws + 589824);       // 512*512*2 = 524288
  u16*      W2 = (u16*)(ws + 1114112);
  u16*      W3 = (u16*)(ws + 1638400);
  float*    W4 = (float*)(ws + 2162688);    // 3*512*4 = 6144
  u16*      TB = (u16*)(ws + 2168832);      // 320*2 = 640 (pad to 2304)
  u16*      Ix = (u16*)(ws + 2171136);      // 32768*24*2 = 1572864
  float*    Pp = (float*)(ws + 2171136);    // overlays Ix (dead after gstats):
                                            // 2*32768*4*4 = 1048576 < 1572864
  float*    Pb = (float*)(ws + 3744000);    // 32768*12*4 = 1572864
  u16*      X  = (u16*)(ws + 5316864);      // 32768*576*2 = 37748736 (permuted cols)
  u16*      H1 = (u16*)(ws + 43065600);     // 32768*512*2 = 33554432
  u16*      H2 = X;  // X not needed after layer 0; reuse as ping-pong buffer

  prep_all<<<2050, 64, 0, stream>>>(v0, g0, v1, g1, v2, g2, v3, g3, v4, g4,
                                    W0, W1, W2, W3, W4, TB);

  scan_kernel<<<8192, 256, 0, stream>>>(pts, phys, Ix);
  gstats_kernel<<<128, 256, 0, stream>>>(pts, phys, cam, Ix, Pb);
  emb_kernel<<<4096, dim3(72, 8), 0, stream>>>(pts, nrm, vdir, fv, rdir, Pb, TB, X);

  gemm_relu<9, false><<<256, 512, 0, stream>>>(X,  W0, b0, H1, nullptr, nullptr);
  gemm_relu<8, false><<<256, 512, 0, stream>>>(H1, W1, b1, H2, nullptr, nullptr);
  gemm_relu<8, false><<<256, 512, 0, stream>>>(H2, W2, b2, H1, nullptr, nullptr);
  gemm_relu<8, true ><<<256, 512, 0, stream>>>(H1, W3, b3, nullptr, W4, Pp);

  sigmoid_kernel<<<128, 256, 0, stream>>>(Pp, b4, (float*)d_out);
}